// Round 4
// baseline (508.303 us; speedup 1.0000x reference)
//
#include <hip/hip_runtime.h>
#include <hip/hip_fp16.h>
#include <stdint.h>

#define N_NODES 100000
#define N_EDGES 3200000
#define QCH 32
#define QP (QCH / 2)          // 16 half2 pairs per node
#define DT_C 0.1f
#define NXCD 8

// Physical XCD (chiplet) id of the executing wave. Wave-uniform SGPR.
__device__ __forceinline__ int xcc_id() {
    int x;
    asm volatile("s_getreg_b32 %0, hwreg(HW_REG_XCC_ID)" : "=s"(x));
    return x & (NXCD - 1);
}

// Packed fp16 atomic add WITHOUT sc1: executes in the local XCD's L2
// (no write-through to the device coherence point). Only safe because every
// wave touching a given buffer copy is on that copy's XCD.
__device__ __forceinline__ void atomic_pk_add_f16_l2(__half2* p, __half2 v) {
    asm volatile("global_atomic_pk_add_f16 %0, %1, off"
                 :: "v"((uint64_t)(uintptr_t)p),
                    "v"(*(const unsigned int*)&v)
                 : "memory");
}

// Kernel 1: out-degree of each node (float, matches segment_sum of ones)
__global__ void deg_kernel(const int* __restrict__ src,
                           float* __restrict__ deg, int E) {
    int e = blockIdx.x * blockDim.x + threadIdx.x;
    if (e < E) atomicAdd(&deg[src[e]], 1.0f);
}

// Kernel 2: one thread per (edge, q-pair). Packed atomics into the
// executing XCD's private accumulator copy (L2-local RMW).
__global__ void edge_kernel_h2x(const float2* __restrict__ f2,
                                const float* __restrict__ w,
                                const int* __restrict__ src,
                                const int* __restrict__ dst,
                                const float* __restrict__ deg,
                                __half2* __restrict__ trans8,  // [NXCD][N*QP]
                                int E) {
    long long t = (long long)blockIdx.x * blockDim.x + threadIdx.x;
    int e = (int)(t >> 4);
    int qp = (int)(t & 15);
    if (e >= E) return;
    __half2* my = trans8 + (size_t)xcc_id() * ((size_t)N_NODES * QP);
    int s = src[e];
    int d = dst[e];
    float coef = w[e] / fmaxf(deg[s], 1.0f);
    float2 fs = f2[s * QP + qp];
    float2 fd = f2[d * QP + qp];
    float xi0 = (75.0f / 31.0f) * (float)(2 * qp);
    float xi1 = (75.0f / 31.0f) * (float)(2 * qp + 1);
    float m0 = coef * xi0 * (fmaxf(fd.x, 0.0f) - fmaxf(fs.x, 0.0f));
    float m1 = coef * xi1 * (fmaxf(fd.y, 0.0f) - fmaxf(fs.y, 0.0f));
    __half2 mp = __floats2half2_rn(m0, m1);
    __half2 mn = __floats2half2_rn(-m0, -m1);
    atomic_pk_add_f16_l2(&my[s * QP + qp], mp);   // outflow at src
    atomic_pk_add_f16_l2(&my[d * QP + qp], mn);   // -inflow at dst
}

// Kernel 3: reduce the 8 XCD copies + finalize, one thread per q-pair.
__global__ void final_reduce(const float2* __restrict__ fdist,
                             const float2* __restrict__ coll,
                             const float2* __restrict__ srct,
                             const __half2* __restrict__ trans8,
                             float2* __restrict__ out, int n2) {
    int i = blockIdx.x * blockDim.x + threadIdx.x;
    if (i >= n2) return;
    float tx = 0.0f, ty = 0.0f;
#pragma unroll
    for (int x = 0; x < NXCD; ++x) {
        float2 v = __half22float2(trans8[(size_t)x * n2 + i]);
        tx += v.x;
        ty += v.y;
    }
    float2 fr = fdist[i];
    float2 cl = coll[i];
    float2 st = srct[i];
    float f0 = fmaxf(fr.x, 0.0f);
    float f1 = fmaxf(fr.y, 0.0f);
    float2 o;
    o.x = fmaxf(f0 - DT_C * (tx - cl.x - st.x), 0.0f);
    o.y = fmaxf(f1 - DT_C * (ty - cl.y - st.y), 0.0f);
    out[i] = o;
}

extern "C" void kernel_launch(void* const* d_in, const int* in_sizes, int n_in,
                              void* d_out, int out_size, void* d_ws, size_t ws_size,
                              hipStream_t stream) {
    const float* f    = (const float*)d_in[0];  // [N, Q]
    const float* coll = (const float*)d_in[1];  // [N, Q]
    const float* srct = (const float*)d_in[2];  // [N, Q]
    const float* w    = (const float*)d_in[3];  // [E]
    const int*   src  = (const int*)d_in[4];    // [E]
    const int*   dst  = (const int*)d_in[5];    // [E]
    float* out = (float*)d_out;                 // [N, Q]

    const int N = N_NODES;
    const int E = N_EDGES;

    const size_t TRANS_BYTES = (size_t)NXCD * N * QP * sizeof(__half2); // 51.2 MB
    __half2* trans8 = (__half2*)d_ws;
    float* deg = (float*)((char*)d_ws + TRANS_BYTES);                    // +400 KB

    // zero trans copies + deg in one contiguous memset
    hipMemsetAsync(d_ws, 0, TRANS_BYTES + (size_t)N * sizeof(float), stream);

    deg_kernel<<<(E + 255) / 256, 256, 0, stream>>>(src, deg, E);

    long long total = (long long)E * QP;
    int blocks = (int)((total + 255) / 256);
    edge_kernel_h2x<<<blocks, 256, 0, stream>>>((const float2*)f, w, src, dst,
                                                deg, trans8, E);

    int n2 = N * QP;
    final_reduce<<<(n2 + 255) / 256, 256, 0, stream>>>((const float2*)f,
                                                       (const float2*)coll,
                                                       (const float2*)srct,
                                                       trans8, (float2*)out, n2);
}